// Round 1
// baseline (2282.340 us; speedup 1.0000x reference)
//
#include <hip/hip_runtime.h>

// GraphSAGE 3-layer encoder, fp32 baseline.
// Layer: sum/cnt scatter (atomics) -> compute: out = mean@Wl + x@Wr + b, PReLU.

constexpr int cN0 = 400000, cN1 = 200000, cN2 = 100000, cN3 = 50000;
constexpr int cE1 = 500000, cE2 = 300000, cE3 = 150000;

#define NDIV_UP(a, b) (((a) + (b) - 1) / (b))

// Detect whether index buffers are int64 (JAX x64 on) or int32 (default).
// If data were int32, int64 interpretation of pairs (a, b) = a + b*2^32 >= 2^32
// for any b>0, which is >= nmax -> flag=0. All-valid int64 reads -> flag=1.
__global__ void detect_idx64_kernel(const void* __restrict__ src, int E,
                                    long long nmax, int* __restrict__ flag) {
  if (threadIdx.x == 0 && blockIdx.x == 0) {
    const long long* p = (const long long*)src;
    int n = E < 512 ? E : 512;
    int ok = 1;
    for (int i = 0; i < n; ++i) {
      long long v = p[i];
      if (v < 0 || v >= nmax) { ok = 0; break; }
    }
    *flag = ok;
  }
}

// 32 lanes per edge; each lane gathers float4 (16B) of the source row and
// atomically accumulates into the destination row. Lane 0 bumps the count.
__global__ void scatter_kernel(const float* __restrict__ hsrc,
                               const void* __restrict__ srcv,
                               const void* __restrict__ dstv,
                               const int* __restrict__ flag,
                               float* __restrict__ sum,
                               float* __restrict__ cnt, int E) {
  int t = blockIdx.x * 256 + threadIdx.x;
  int e = t >> 5;
  if (e >= E) return;
  int q = t & 31;
  int s, d;
  if (*flag) {
    s = (int)((const long long*)srcv)[e];
    d = (int)((const long long*)dstv)[e];
  } else {
    s = ((const int*)srcv)[e];
    d = ((const int*)dstv)[e];
  }
  const float4 v = *(const float4*)(hsrc + (size_t)s * 128 + q * 4);
  float* sp = sum + (size_t)d * 128 + q * 4;
  atomicAdd(sp + 0, v.x);
  atomicAdd(sp + 1, v.y);
  atomicAdd(sp + 2, v.z);
  atomicAdd(sp + 3, v.w);
  if (q == 0) atomicAdd(cnt + d, 1.0f);
}

// Block = 256 threads computes a 32-row x 128-col output tile.
// mean/x staged TRANSPOSED in LDS (pad 36 words -> 16B-aligned b128 reads),
// W staged in LDS in K-tiles of 16. Per-thread 4x4 register tile.
// out may alias sum (rows are fully staged to LDS before any write).
__global__ __launch_bounds__(256) void compute_kernel(
    const float* __restrict__ sum, const float* __restrict__ cnt,
    const float* __restrict__ xdst,
    const float* __restrict__ Wl, const float* __restrict__ Wr,
    const float* __restrict__ bias, const float* __restrict__ alpha,
    float* __restrict__ out, int n) {
  __shared__ __align__(16) float mt[128][36];  // mean^T [k][row]
  __shared__ __align__(16) float xt[128][36];  // x^T    [k][row]
  __shared__ __align__(16) float wl[16][132];  // Wl tile [kk][col]
  __shared__ __align__(16) float wr[16][132];  // Wr tile [kk][col]

  const int tid = threadIdx.x;
  const int r0 = blockIdx.x * 32;

  // Stage mean (sum/cnt) and x_dst, transposed.
  for (int idx = tid; idx < 32 * 128; idx += 256) {
    int r = idx >> 7, k = idx & 127;
    int row = r0 + r;
    float m = 0.f, xv = 0.f;
    if (row < n) {
      float c = cnt[row];
      float inv = 1.0f / fmaxf(c, 1.0f);
      m = sum[(size_t)row * 128 + k] * inv;
      xv = xdst[(size_t)row * 128 + k];
    }
    mt[k][r] = m;
    xt[k][r] = xv;
  }

  const int jt = tid & 31;  // col group: cols 4*jt .. 4*jt+3
  const int rt = tid >> 5;  // row group: rows 4*rt .. 4*rt+3
  float acc[4][4] = {};

  for (int k0 = 0; k0 < 128; k0 += 16) {
    __syncthreads();  // also covers initial mean/x staging on first iter
    for (int idx = tid; idx < 16 * 32; idx += 256) {
      int kk = idx >> 5, cq = idx & 31;
      *(float4*)(&wl[kk][cq * 4]) = *(const float4*)(Wl + (k0 + kk) * 128 + cq * 4);
      *(float4*)(&wr[kk][cq * 4]) = *(const float4*)(Wr + (k0 + kk) * 128 + cq * 4);
    }
    __syncthreads();
#pragma unroll
    for (int kk = 0; kk < 16; ++kk) {
      const float4 m4 = *(const float4*)(&mt[k0 + kk][rt * 4]);
      const float4 x4 = *(const float4*)(&xt[k0 + kk][rt * 4]);
      const float4 l4 = *(const float4*)(&wl[kk][jt * 4]);
      const float4 r4 = *(const float4*)(&wr[kk][jt * 4]);
      const float mm[4] = {m4.x, m4.y, m4.z, m4.w};
      const float xx[4] = {x4.x, x4.y, x4.z, x4.w};
      const float ll[4] = {l4.x, l4.y, l4.z, l4.w};
      const float rr[4] = {r4.x, r4.y, r4.z, r4.w};
#pragma unroll
      for (int r = 0; r < 4; ++r)
#pragma unroll
        for (int c = 0; c < 4; ++c)
          acc[r][c] += mm[r] * ll[c] + xx[r] * rr[c];
    }
  }

  const float4 b4 = *(const float4*)(bias + jt * 4);
  const float4 a4 = *(const float4*)(alpha + jt * 4);
  const float bb[4] = {b4.x, b4.y, b4.z, b4.w};
  const float aa[4] = {a4.x, a4.y, a4.z, a4.w};
#pragma unroll
  for (int r = 0; r < 4; ++r) {
    int row = r0 + rt * 4 + r;
    if (row < n) {
      float4 o;
      float* op = (float*)&o;
#pragma unroll
      for (int c = 0; c < 4; ++c) {
        float v = acc[r][c] + bb[c];
        op[c] = v > 0.f ? v : aa[c] * v;
      }
      *(float4*)(out + (size_t)row * 128 + jt * 4) = o;
    }
  }
}

extern "C" void kernel_launch(void* const* d_in, const int* in_sizes, int n_in,
                              void* d_out, int out_size, void* d_ws, size_t ws_size,
                              hipStream_t stream) {
  const float* x = (const float*)d_in[0];
  const void* src1 = d_in[1];
  const void* dst1 = d_in[2];
  const void* src2 = d_in[3];
  const void* dst2 = d_in[4];
  const void* src3 = d_in[5];
  const void* dst3 = d_in[6];
  const float* Wl1 = (const float*)d_in[7];
  const float* Wr1 = (const float*)d_in[8];
  const float* b1  = (const float*)d_in[9];
  const float* a1  = (const float*)d_in[10];
  const float* Wl2 = (const float*)d_in[11];
  const float* Wr2 = (const float*)d_in[12];
  const float* b2  = (const float*)d_in[13];
  const float* a2  = (const float*)d_in[14];
  const float* Wl3 = (const float*)d_in[15];
  const float* Wr3 = (const float*)d_in[16];
  const float* b3  = (const float*)d_in[17];
  const float* a3  = (const float*)d_in[18];

  // Workspace layout: A (N1*128), B (N2*128), cnt (N1), flag (1 int)
  float* A = (float*)d_ws;
  float* B = A + (size_t)cN1 * 128;
  float* cnt = B + (size_t)cN2 * 128;
  int* flag = (int*)(cnt + cN1);

  detect_idx64_kernel<<<1, 64, 0, stream>>>(src1, cE1, (long long)cN0, flag);

  // ---- Layer 1: x (N0) --edges1--> h1 (N1), h1 stored in-place in A ----
  hipMemsetAsync(A, 0, (size_t)cN1 * 128 * sizeof(float), stream);
  hipMemsetAsync(cnt, 0, (size_t)cN1 * sizeof(float), stream);
  scatter_kernel<<<NDIV_UP(cE1 * 32, 256), 256, 0, stream>>>(x, src1, dst1, flag, A, cnt, cE1);
  compute_kernel<<<NDIV_UP(cN1, 32), 256, 0, stream>>>(A, cnt, x, Wl1, Wr1, b1, a1, A, cN1);

  // ---- Layer 2: h1 (A) --edges2--> h2 (N2), stored in-place in B ----
  hipMemsetAsync(B, 0, (size_t)cN2 * 128 * sizeof(float), stream);
  hipMemsetAsync(cnt, 0, (size_t)cN2 * sizeof(float), stream);
  scatter_kernel<<<NDIV_UP(cE2 * 32, 256), 256, 0, stream>>>(A, src2, dst2, flag, B, cnt, cE2);
  compute_kernel<<<NDIV_UP(cN2, 32), 256, 0, stream>>>(B, cnt, A, Wl2, Wr2, b2, a2, B, cN2);

  // ---- Layer 3: h2 (B) --edges3--> out (N3), sums in A, out -> d_out ----
  hipMemsetAsync(A, 0, (size_t)cN3 * 128 * sizeof(float), stream);
  hipMemsetAsync(cnt, 0, (size_t)cN3 * sizeof(float), stream);
  scatter_kernel<<<NDIV_UP(cE3 * 32, 256), 256, 0, stream>>>(B, src3, dst3, flag, A, cnt, cE3);
  compute_kernel<<<NDIV_UP(cN3, 32), 256, 0, stream>>>(A, cnt, B, Wl3, Wr3, b3, a3, (float*)d_out, cN3);
}

// Round 2
// 906.462 us; speedup vs baseline: 2.5179x; 2.5179x over previous
//
#include <hip/hip_runtime.h>

// GraphSAGE 3-layer encoder.
// Per layer: CSR build (hist -> scan -> fill) -> gather-mean (no atomics on
// feature data) -> compute: out = mean@Wl + b + x@Wr, PReLU.

constexpr int cN0 = 400000, cN1 = 200000, cN2 = 100000, cN3 = 50000;
constexpr int cE1 = 500000, cE2 = 300000, cE3 = 150000;

#define NDIV_UP(a, b) (((a) + (b) - 1) / (b))

// Detect whether index buffers are int64 (JAX x64) or int32.
__global__ void detect_idx64_kernel(const void* __restrict__ src, int E,
                                    long long nmax, int* __restrict__ flag) {
  if (threadIdx.x == 0 && blockIdx.x == 0) {
    const long long* p = (const long long*)src;
    int n = E < 512 ? E : 512;
    int ok = 1;
    for (int i = 0; i < n; ++i) {
      long long v = p[i];
      if (v < 0 || v >= nmax) { ok = 0; break; }
    }
    *flag = ok;
  }
}

__device__ __forceinline__ int load_idx(const void* p, int i, int flag) {
  return flag ? (int)((const long long*)p)[i] : ((const int*)p)[i];
}

__global__ void hist_kernel(const void* __restrict__ dstv,
                            const int* __restrict__ flag,
                            int* __restrict__ cnt, int E) {
  int e = blockIdx.x * 256 + threadIdx.x;
  if (e >= E) return;
  atomicAdd(&cnt[load_idx(dstv, e, *flag)], 1);
}

// ---- exclusive scan over cnt[n] -> offs[n], 1024 items / block ----
__global__ __launch_bounds__(256) void scan_reduce(const int* __restrict__ cnt,
                                                   int n, int* __restrict__ bsum) {
  __shared__ int s[256];
  int t = threadIdx.x;
  int base = blockIdx.x * 1024 + t * 4;
  int v = 0;
  if (base + 3 < n) {
    int4 c = *(const int4*)(cnt + base);
    v = c.x + c.y + c.z + c.w;
  } else {
    for (int i = 0; i < 4; ++i)
      if (base + i < n) v += cnt[base + i];
  }
  s[t] = v;
  __syncthreads();
  for (int off = 128; off > 0; off >>= 1) {
    if (t < off) s[t] += s[t + off];
    __syncthreads();
  }
  if (t == 0) bsum[blockIdx.x] = s[0];
}

__global__ void scan_bsums(int* __restrict__ bsum, int nb) {
  if (threadIdx.x == 0 && blockIdx.x == 0) {
    int acc = 0;
    for (int i = 0; i < nb; ++i) {
      int t = bsum[i];
      bsum[i] = acc;
      acc += t;
    }
  }
}

__global__ __launch_bounds__(256) void scan_final(const int* __restrict__ cnt,
                                                  int n, const int* __restrict__ bsum,
                                                  int* __restrict__ offs) {
  __shared__ int s[256];
  int t = threadIdx.x;
  int base = blockIdx.x * 1024 + t * 4;
  int v0 = 0, v1 = 0, v2 = 0, v3 = 0;
  if (base + 3 < n) {
    int4 c = *(const int4*)(cnt + base);
    v0 = c.x; v1 = c.y; v2 = c.z; v3 = c.w;
  } else {
    if (base + 0 < n) v0 = cnt[base + 0];
    if (base + 1 < n) v1 = cnt[base + 1];
    if (base + 2 < n) v2 = cnt[base + 2];
  }
  int tsum = v0 + v1 + v2 + v3;
  s[t] = tsum;
  __syncthreads();
  for (int off = 1; off < 256; off <<= 1) {
    int x = (t >= off) ? s[t - off] : 0;
    __syncthreads();
    s[t] += x;
    __syncthreads();
  }
  int excl = s[t] - tsum;
  int o = bsum[blockIdx.x] + excl;
  if (base + 0 < n) offs[base + 0] = o;
  o += v0;
  if (base + 1 < n) offs[base + 1] = o;
  o += v1;
  if (base + 2 < n) offs[base + 2] = o;
  o += v2;
  if (base + 3 < n) offs[base + 3] = o;
}

// Bucket-fill: advances offs[d]; post-fill offs[d] == pre-fill offs[d+1].
__global__ void fill_kernel(const void* __restrict__ srcv,
                            const void* __restrict__ dstv,
                            const int* __restrict__ flag,
                            int* __restrict__ offs, int* __restrict__ eid, int E) {
  int e = blockIdx.x * 256 + threadIdx.x;
  if (e >= E) return;
  int f = *flag;
  int s = load_idx(srcv, e, f);
  int d = load_idx(dstv, e, f);
  int pos = atomicAdd(&offs[d], 1);
  eid[pos] = s;
}

// One wave (64 lanes) per destination row; lane owns 2 columns (float2).
// start = row ? offs[row-1] : 0, end = offs[row]  (post-fill convention).
__global__ __launch_bounds__(256) void gather_mean_kernel(
    const float* __restrict__ hsrc, const int* __restrict__ offs,
    const int* __restrict__ eid, float* __restrict__ mean, int n) {
  int row = blockIdx.x * 4 + (threadIdx.x >> 6);
  if (row >= n) return;
  int lane = threadIdx.x & 63;
  int start = row ? offs[row - 1] : 0;
  int end = offs[row];
  float ax = 0.f, ay = 0.f;
  for (int i = start; i < end; ++i) {
    const float2 v = *(const float2*)(hsrc + (size_t)eid[i] * 128 + lane * 2);
    ax += v.x;
    ay += v.y;
  }
  float inv = (end > start) ? 1.0f / (float)(end - start) : 0.0f;
  *(float2*)(mean + (size_t)row * 128 + lane * 2) = make_float2(ax * inv, ay * inv);
}

// Block = 256 threads computes a 32-row x 128-col output tile.
// mean/x staged TRANSPOSED in LDS; W staged in K-tiles of 16; 4x4 reg tile.
// out may alias mean (rows fully staged to LDS before any write).
__global__ __launch_bounds__(256) void compute_kernel(
    const float* __restrict__ mean, const float* __restrict__ xdst,
    const float* __restrict__ Wl, const float* __restrict__ Wr,
    const float* __restrict__ bias, const float* __restrict__ alpha,
    float* __restrict__ out, int n) {
  __shared__ __align__(16) float mt[128][36];
  __shared__ __align__(16) float xt[128][36];
  __shared__ __align__(16) float wl[16][132];
  __shared__ __align__(16) float wr[16][132];

  const int tid = threadIdx.x;
  const int r0 = blockIdx.x * 32;

  for (int idx = tid; idx < 32 * 128; idx += 256) {
    int r = idx >> 7, k = idx & 127;
    int row = r0 + r;
    float m = 0.f, xv = 0.f;
    if (row < n) {
      m = mean[(size_t)row * 128 + k];
      xv = xdst[(size_t)row * 128 + k];
    }
    mt[k][r] = m;
    xt[k][r] = xv;
  }

  const int jt = tid & 31;
  const int rt = tid >> 5;
  float acc[4][4] = {};

  for (int k0 = 0; k0 < 128; k0 += 16) {
    __syncthreads();
    for (int idx = tid; idx < 16 * 32; idx += 256) {
      int kk = idx >> 5, cq = idx & 31;
      *(float4*)(&wl[kk][cq * 4]) = *(const float4*)(Wl + (k0 + kk) * 128 + cq * 4);
      *(float4*)(&wr[kk][cq * 4]) = *(const float4*)(Wr + (k0 + kk) * 128 + cq * 4);
    }
    __syncthreads();
#pragma unroll
    for (int kk = 0; kk < 16; ++kk) {
      const float4 m4 = *(const float4*)(&mt[k0 + kk][rt * 4]);
      const float4 x4 = *(const float4*)(&xt[k0 + kk][rt * 4]);
      const float4 l4 = *(const float4*)(&wl[kk][jt * 4]);
      const float4 r4 = *(const float4*)(&wr[kk][jt * 4]);
      const float mm[4] = {m4.x, m4.y, m4.z, m4.w};
      const float xx[4] = {x4.x, x4.y, x4.z, x4.w};
      const float ll[4] = {l4.x, l4.y, l4.z, l4.w};
      const float rr[4] = {r4.x, r4.y, r4.z, r4.w};
#pragma unroll
      for (int r = 0; r < 4; ++r)
#pragma unroll
        for (int c = 0; c < 4; ++c)
          acc[r][c] += mm[r] * ll[c] + xx[r] * rr[c];
    }
  }

  const float4 b4 = *(const float4*)(bias + jt * 4);
  const float4 a4 = *(const float4*)(alpha + jt * 4);
  const float bb[4] = {b4.x, b4.y, b4.z, b4.w};
  const float aa[4] = {a4.x, a4.y, a4.z, a4.w};
#pragma unroll
  for (int r = 0; r < 4; ++r) {
    int row = r0 + rt * 4 + r;
    if (row < n) {
      float4 o;
      float* op = (float*)&o;
#pragma unroll
      for (int c = 0; c < 4; ++c) {
        float v = acc[r][c] + bb[c];
        op[c] = v > 0.f ? v : aa[c] * v;
      }
      *(float4*)(out + (size_t)row * 128 + jt * 4) = o;
    }
  }
}

static void run_layer(const float* hsrc, const float* xdst, const void* src,
                      const void* dst, const int* flag, int E, int n,
                      int* cnt, int* offs, int* eid, int* bsum, float* mean,
                      const float* Wl, const float* Wr, const float* b,
                      const float* a, float* out, hipStream_t stream) {
  int nb = NDIV_UP(n, 1024);
  hipMemsetAsync(cnt, 0, (size_t)n * sizeof(int), stream);
  hist_kernel<<<NDIV_UP(E, 256), 256, 0, stream>>>(dst, flag, cnt, E);
  scan_reduce<<<nb, 256, 0, stream>>>(cnt, n, bsum);
  scan_bsums<<<1, 64, 0, stream>>>(bsum, nb);
  scan_final<<<nb, 256, 0, stream>>>(cnt, n, bsum, offs);
  fill_kernel<<<NDIV_UP(E, 256), 256, 0, stream>>>(src, dst, flag, offs, eid, E);
  gather_mean_kernel<<<NDIV_UP(n, 4), 256, 0, stream>>>(hsrc, offs, eid, mean, n);
  compute_kernel<<<NDIV_UP(n, 32), 256, 0, stream>>>(mean, xdst, Wl, Wr, b, a, out, n);
}

extern "C" void kernel_launch(void* const* d_in, const int* in_sizes, int n_in,
                              void* d_out, int out_size, void* d_ws, size_t ws_size,
                              hipStream_t stream) {
  const float* x = (const float*)d_in[0];
  const void* src1 = d_in[1];
  const void* dst1 = d_in[2];
  const void* src2 = d_in[3];
  const void* dst2 = d_in[4];
  const void* src3 = d_in[5];
  const void* dst3 = d_in[6];
  const float* Wl1 = (const float*)d_in[7];
  const float* Wr1 = (const float*)d_in[8];
  const float* b1  = (const float*)d_in[9];
  const float* a1  = (const float*)d_in[10];
  const float* Wl2 = (const float*)d_in[11];
  const float* Wr2 = (const float*)d_in[12];
  const float* b2  = (const float*)d_in[13];
  const float* a2  = (const float*)d_in[14];
  const float* Wl3 = (const float*)d_in[15];
  const float* Wr3 = (const float*)d_in[16];
  const float* b3  = (const float*)d_in[17];
  const float* a3  = (const float*)d_in[18];

  // ws layout: A (N1*128 f), B (N2*128 f), cnt (N1 i), offs (N1 i),
  //            eid (E1 i), bsum (1024 i), flag (1 i)
  float* A = (float*)d_ws;
  float* B = A + (size_t)cN1 * 128;
  int* cnt = (int*)(B + (size_t)cN2 * 128);
  int* offs = cnt + cN1;
  int* eid = offs + cN1;
  int* bsum = eid + cE1;
  int* flag = bsum + 1024;

  detect_idx64_kernel<<<1, 64, 0, stream>>>(src1, cE1, (long long)cN0, flag);

  // Layer 1: x (N0) -> h1 in A (N1)
  run_layer(x, x, src1, dst1, flag, cE1, cN1, cnt, offs, eid, bsum, A,
            Wl1, Wr1, b1, a1, A, stream);
  // Layer 2: h1 (A) -> h2 in B (N2)
  run_layer(A, A, src2, dst2, flag, cE2, cN2, cnt, offs, eid, bsum, B,
            Wl2, Wr2, b2, a2, B, stream);
  // Layer 3: h2 (B) -> out (N3)
  run_layer(B, B, src3, dst3, flag, cE3, cN3, cnt, offs, eid, bsum, A,
            Wl3, Wr3, b3, a3, (float*)d_out, stream);
}

// Round 3
// 627.056 us; speedup vs baseline: 3.6398x; 1.4456x over previous
//
#include <hip/hip_runtime.h>

// GraphSAGE 3-layer encoder.
// Per layer: CSR build (hist -> scan -> fill) -> gather-mean (no atomics on
// feature data) -> MFMA compute: out = mean@Wl + b + x@Wr, PReLU.
// GEMMs use split-bf16 (hi+lo) 3-term MFMA for ~fp32 accuracy.

constexpr int cN0 = 400000, cN1 = 200000, cN2 = 100000, cN3 = 50000;
constexpr int cE1 = 500000, cE2 = 300000, cE3 = 150000;

#define NDIV_UP(a, b) (((a) + (b) - 1) / (b))

typedef __attribute__((ext_vector_type(8))) short bf16x8;
typedef __attribute__((ext_vector_type(4))) float f32x4;

__device__ __forceinline__ unsigned short f2bf(float f) {
  unsigned u = __builtin_bit_cast(unsigned, f);
  unsigned r = u + 0x7FFFu + ((u >> 16) & 1u);
  return (unsigned short)(r >> 16);
}
__device__ __forceinline__ float bf2f(unsigned short h) {
  return __builtin_bit_cast(float, (unsigned)h << 16);
}

// Detect whether index buffers are int64 (JAX x64) or int32.
__global__ void detect_idx64_kernel(const void* __restrict__ src, int E,
                                    long long nmax, int* __restrict__ flag) {
  if (threadIdx.x == 0 && blockIdx.x == 0) {
    const long long* p = (const long long*)src;
    int n = E < 512 ? E : 512;
    int ok = 1;
    for (int i = 0; i < n; ++i) {
      long long v = p[i];
      if (v < 0 || v >= nmax) { ok = 0; break; }
    }
    *flag = ok;
  }
}

__device__ __forceinline__ int load_idx(const void* p, int i, int flag) {
  return flag ? (int)((const long long*)p)[i] : ((const int*)p)[i];
}

__global__ void hist_kernel(const void* __restrict__ dstv,
                            const int* __restrict__ flag,
                            int* __restrict__ cnt, int E) {
  int e = blockIdx.x * 256 + threadIdx.x;
  if (e >= E) return;
  atomicAdd(&cnt[load_idx(dstv, e, *flag)], 1);
}

// ---- exclusive scan over cnt[n] -> offs[n], 1024 items / block ----
__global__ __launch_bounds__(256) void scan_reduce(const int* __restrict__ cnt,
                                                   int n, int* __restrict__ bsum) {
  __shared__ int s[256];
  int t = threadIdx.x;
  int base = blockIdx.x * 1024 + t * 4;
  int v = 0;
  if (base + 3 < n) {
    int4 c = *(const int4*)(cnt + base);
    v = c.x + c.y + c.z + c.w;
  } else {
    for (int i = 0; i < 4; ++i)
      if (base + i < n) v += cnt[base + i];
  }
  s[t] = v;
  __syncthreads();
  for (int off = 128; off > 0; off >>= 1) {
    if (t < off) s[t] += s[t + off];
    __syncthreads();
  }
  if (t == 0) bsum[blockIdx.x] = s[0];
}

__global__ void scan_bsums(int* __restrict__ bsum, int nb) {
  if (threadIdx.x == 0 && blockIdx.x == 0) {
    int acc = 0;
    for (int i = 0; i < nb; ++i) {
      int t = bsum[i];
      bsum[i] = acc;
      acc += t;
    }
  }
}

__global__ __launch_bounds__(256) void scan_final(const int* __restrict__ cnt,
                                                  int n, const int* __restrict__ bsum,
                                                  int* __restrict__ offs) {
  __shared__ int s[256];
  int t = threadIdx.x;
  int base = blockIdx.x * 1024 + t * 4;
  int v0 = 0, v1 = 0, v2 = 0, v3 = 0;
  if (base + 3 < n) {
    int4 c = *(const int4*)(cnt + base);
    v0 = c.x; v1 = c.y; v2 = c.z; v3 = c.w;
  } else {
    if (base + 0 < n) v0 = cnt[base + 0];
    if (base + 1 < n) v1 = cnt[base + 1];
    if (base + 2 < n) v2 = cnt[base + 2];
  }
  int tsum = v0 + v1 + v2 + v3;
  s[t] = tsum;
  __syncthreads();
  for (int off = 1; off < 256; off <<= 1) {
    int x = (t >= off) ? s[t - off] : 0;
    __syncthreads();
    s[t] += x;
    __syncthreads();
  }
  int excl = s[t] - tsum;
  int o = bsum[blockIdx.x] + excl;
  if (base + 0 < n) offs[base + 0] = o;
  o += v0;
  if (base + 1 < n) offs[base + 1] = o;
  o += v1;
  if (base + 2 < n) offs[base + 2] = o;
  o += v2;
  if (base + 3 < n) offs[base + 3] = o;
}

// Bucket-fill: advances offs[d]; post-fill offs[d] == pre-fill offs[d+1].
__global__ void fill_kernel(const void* __restrict__ srcv,
                            const void* __restrict__ dstv,
                            const int* __restrict__ flag,
                            int* __restrict__ offs, int* __restrict__ eid, int E) {
  int e = blockIdx.x * 256 + threadIdx.x;
  if (e >= E) return;
  int f = *flag;
  int s = load_idx(srcv, e, f);
  int d = load_idx(dstv, e, f);
  int pos = atomicAdd(&offs[d], 1);
  eid[pos] = s;
}

// One wave (64 lanes) per destination row; lane owns 2 columns (float2).
__global__ __launch_bounds__(256) void gather_mean_kernel(
    const float* __restrict__ hsrc, const int* __restrict__ offs,
    const int* __restrict__ eid, float* __restrict__ mean, int n) {
  int row = blockIdx.x * 4 + (threadIdx.x >> 6);
  if (row >= n) return;
  int lane = threadIdx.x & 63;
  int start = row ? offs[row - 1] : 0;
  int end = offs[row];
  float ax = 0.f, ay = 0.f;
  for (int i = start; i < end; ++i) {
    const float2 v = *(const float2*)(hsrc + (size_t)eid[i] * 128 + lane * 2);
    ax += v.x;
    ay += v.y;
  }
  float inv = (end > start) ? 1.0f / (float)(end - start) : 0.0f;
  *(float2*)(mean + (size_t)row * 128 + lane * 2) = make_float2(ax * inv, ay * inv);
}

// Pre-pack weights into per-lane MFMA B-fragment order, split bf16 hi/lo.
// idx = ((ks*8 + cf)*64 + lane)*8 + j ; k = ks*32 + (lane>>4)*8 + j ;
// col = cf*16 + (lane&15). Each (ks,cf) chunk is 1KB contiguous.
__global__ void pack_w_kernel(const float* __restrict__ Wl,
                              const float* __restrict__ Wr,
                              unsigned short* __restrict__ Wlh,
                              unsigned short* __restrict__ Wll,
                              unsigned short* __restrict__ Wrh,
                              unsigned short* __restrict__ Wrl) {
  int idx = blockIdx.x * 256 + threadIdx.x;
  if (idx >= 16384) return;
  int j = idx & 7, l = (idx >> 3) & 63, cf = (idx >> 9) & 7, ks = idx >> 12;
  int k = ks * 32 + (l >> 4) * 8 + j;
  int col = cf * 16 + (l & 15);
  float vl = Wl[k * 128 + col];
  float vr = Wr[k * 128 + col];
  unsigned short h;
  h = f2bf(vl);
  Wlh[idx] = h;
  Wll[idx] = f2bf(vl - bf2f(h));
  h = f2bf(vr);
  Wrh[idx] = h;
  Wrl[idx] = f2bf(vr - bf2f(h));
}

// MFMA compute: block = 4 waves, each wave does a 16-row x 128-col tile.
// No LDS. A-frags (mean, x) loaded from global, split to bf16 hi/lo in-reg.
// Split-bf16: acc += mh@Wh + ml@Wh + mh@Wl_lo (per GEMM) -> ~fp32 accuracy.
// out may alias mean: each wave reads only the rows it writes, reads precede
// the epilogue stores via the acc dependency.
__global__ __launch_bounds__(256) void compute_mfma_kernel(
    const float* __restrict__ mean, const float* __restrict__ xdst,
    const unsigned short* __restrict__ Wlh, const unsigned short* __restrict__ Wll,
    const unsigned short* __restrict__ Wrh, const unsigned short* __restrict__ Wrl,
    const float* __restrict__ bias, const float* __restrict__ alpha,
    float* __restrict__ out, int n) {
  const int lane = threadIdx.x & 63;
  const int wv = threadIdx.x >> 6;
  const int r0 = blockIdx.x * 64 + wv * 16;
  const int arow = r0 + (lane & 15);
  const bool rok = arow < n;
  const int kbase = (lane >> 4) * 8;

  f32x4 acc[8] = {{0.f, 0.f, 0.f, 0.f}};

#pragma unroll
  for (int ks = 0; ks < 4; ++ks) {
    const int k = ks * 32 + kbase;
    float mv[8], xv[8];
    if (rok) {
      const float* mp = mean + (size_t)arow * 128 + k;
      const float* xp = xdst + (size_t)arow * 128 + k;
      *(float4*)&mv[0] = *(const float4*)(mp);
      *(float4*)&mv[4] = *(const float4*)(mp + 4);
      *(float4*)&xv[0] = *(const float4*)(xp);
      *(float4*)&xv[4] = *(const float4*)(xp + 4);
    } else {
#pragma unroll
      for (int j = 0; j < 8; ++j) { mv[j] = 0.f; xv[j] = 0.f; }
    }
    bf16x8 mh, ml, xh, xl;
#pragma unroll
    for (int j = 0; j < 8; ++j) {
      unsigned short h = f2bf(mv[j]);
      mh[j] = (short)h;
      ml[j] = (short)f2bf(mv[j] - bf2f(h));
      h = f2bf(xv[j]);
      xh[j] = (short)h;
      xl[j] = (short)f2bf(xv[j] - bf2f(h));
    }
    const size_t cbase = (size_t)(ks * 8) * 512 + (size_t)lane * 8;
#pragma unroll
    for (int cf = 0; cf < 8; ++cf) {
      const size_t o = cbase + (size_t)cf * 512;
      bf16x8 wlh = *(const bf16x8*)(Wlh + o);
      bf16x8 wll = *(const bf16x8*)(Wll + o);
      bf16x8 wrh = *(const bf16x8*)(Wrh + o);
      bf16x8 wrl = *(const bf16x8*)(Wrl + o);
      acc[cf] = __builtin_amdgcn_mfma_f32_16x16x32_bf16(mh, wlh, acc[cf], 0, 0, 0);
      acc[cf] = __builtin_amdgcn_mfma_f32_16x16x32_bf16(ml, wlh, acc[cf], 0, 0, 0);
      acc[cf] = __builtin_amdgcn_mfma_f32_16x16x32_bf16(mh, wll, acc[cf], 0, 0, 0);
      acc[cf] = __builtin_amdgcn_mfma_f32_16x16x32_bf16(xh, wrh, acc[cf], 0, 0, 0);
      acc[cf] = __builtin_amdgcn_mfma_f32_16x16x32_bf16(xl, wrh, acc[cf], 0, 0, 0);
      acc[cf] = __builtin_amdgcn_mfma_f32_16x16x32_bf16(xh, wrl, acc[cf], 0, 0, 0);
    }
  }

  // Epilogue: C/D layout: col = lane&15, row = (lane>>4)*4 + i (m89-verified).
  const int ocol0 = lane & 15;
  const int orow_b = r0 + (lane >> 4) * 4;
#pragma unroll
  for (int cf = 0; cf < 8; ++cf) {
    const int ocol = cf * 16 + ocol0;
    const float b = bias[ocol];
    const float a = alpha[ocol];
#pragma unroll
    for (int i = 0; i < 4; ++i) {
      const int orow = orow_b + i;
      if (orow < n) {
        float v = acc[cf][i] + b;
        out[(size_t)orow * 128 + ocol] = v > 0.f ? v : a * v;
      }
    }
  }
}

static void run_layer(const float* hsrc, const float* xdst, const void* src,
                      const void* dst, const int* flag, int E, int n,
                      int* cnt, int* offs, int* eid, int* bsum, float* mean,
                      unsigned short* wpk, const float* Wl, const float* Wr,
                      const float* b, const float* a, float* out,
                      hipStream_t stream) {
  unsigned short* Wlh = wpk;
  unsigned short* Wll = wpk + 16384;
  unsigned short* Wrh = wpk + 32768;
  unsigned short* Wrl = wpk + 49152;
  pack_w_kernel<<<64, 256, 0, stream>>>(Wl, Wr, Wlh, Wll, Wrh, Wrl);
  int nb = NDIV_UP(n, 1024);
  hipMemsetAsync(cnt, 0, (size_t)n * sizeof(int), stream);
  hist_kernel<<<NDIV_UP(E, 256), 256, 0, stream>>>(dst, flag, cnt, E);
  scan_reduce<<<nb, 256, 0, stream>>>(cnt, n, bsum);
  scan_bsums<<<1, 64, 0, stream>>>(bsum, nb);
  scan_final<<<nb, 256, 0, stream>>>(cnt, n, bsum, offs);
  fill_kernel<<<NDIV_UP(E, 256), 256, 0, stream>>>(src, dst, flag, offs, eid, E);
  gather_mean_kernel<<<NDIV_UP(n, 4), 256, 0, stream>>>(hsrc, offs, eid, mean, n);
  compute_mfma_kernel<<<NDIV_UP(n, 64), 256, 0, stream>>>(
      mean, xdst, Wlh, Wll, Wrh, Wrl, b, a, out, n);
}

extern "C" void kernel_launch(void* const* d_in, const int* in_sizes, int n_in,
                              void* d_out, int out_size, void* d_ws, size_t ws_size,
                              hipStream_t stream) {
  const float* x = (const float*)d_in[0];
  const void* src1 = d_in[1];
  const void* dst1 = d_in[2];
  const void* src2 = d_in[3];
  const void* dst2 = d_in[4];
  const void* src3 = d_in[5];
  const void* dst3 = d_in[6];
  const float* Wl1 = (const float*)d_in[7];
  const float* Wr1 = (const float*)d_in[8];
  const float* b1  = (const float*)d_in[9];
  const float* a1  = (const float*)d_in[10];
  const float* Wl2 = (const float*)d_in[11];
  const float* Wr2 = (const float*)d_in[12];
  const float* b2  = (const float*)d_in[13];
  const float* a2  = (const float*)d_in[14];
  const float* Wl3 = (const float*)d_in[15];
  const float* Wr3 = (const float*)d_in[16];
  const float* b3  = (const float*)d_in[17];
  const float* a3  = (const float*)d_in[18];

  // ws layout: A (N1*128 f), B (N2*128 f), cnt (N1 i), offs (N1 i),
  //            eid (E1 i), bsum (1024 i), flag+pad (64 i), wpk (4*16384 u16)
  float* A = (float*)d_ws;
  float* B = A + (size_t)cN1 * 128;
  int* cnt = (int*)(B + (size_t)cN2 * 128);
  int* offs = cnt + cN1;
  int* eid = offs + cN1;
  int* bsum = eid + cE1;
  int* flag = bsum + 1024;
  unsigned short* wpk = (unsigned short*)(flag + 64);

  detect_idx64_kernel<<<1, 64, 0, stream>>>(src1, cE1, (long long)cN0, flag);

  // Layer 1: x (N0) -> h1 in A (N1)
  run_layer(x, x, src1, dst1, flag, cE1, cN1, cnt, offs, eid, bsum, A, wpk,
            Wl1, Wr1, b1, a1, A, stream);
  // Layer 2: h1 (A) -> h2 in B (N2)
  run_layer(A, A, src2, dst2, flag, cE2, cN2, cnt, offs, eid, bsum, B, wpk,
            Wl2, Wr2, b2, a2, B, stream);
  // Layer 3: h2 (B) -> out (N3)
  run_layer(B, B, src3, dst3, flag, cE3, cN3, cnt, offs, eid, bsum, A, wpk,
            Wl3, Wr3, b3, a3, (float*)d_out, stream);
}

// Round 4
// 517.931 us; speedup vs baseline: 4.4066x; 1.2107x over previous
//
#include <hip/hip_runtime.h>

// GraphSAGE 3-layer encoder.
// Per layer: CSR build (hist -> scan -> fill) -> gather-mean (writes mean as
// interleaved split-bf16 rows) -> MFMA compute (32 rows/wave, split-bf16
// 3-term products): out = mean@Wl + b + x@Wr, PReLU.

constexpr int cN0 = 400000, cN1 = 200000, cN2 = 100000, cN3 = 50000;
constexpr int cE1 = 500000, cE2 = 300000, cE3 = 150000;

#define NDIV_UP(a, b) (((a) + (b) - 1) / (b))

typedef __attribute__((ext_vector_type(8))) short bf16x8;
typedef __attribute__((ext_vector_type(4))) float f32x4;
typedef __attribute__((ext_vector_type(4))) unsigned u32x4;

__device__ __forceinline__ unsigned fbits(float f) {
  return __builtin_bit_cast(unsigned, f);
}
__device__ __forceinline__ float ffrom(unsigned u) {
  return __builtin_bit_cast(float, u);
}
__device__ __forceinline__ unsigned short f2bf(float f) {  // round-to-nearest
  unsigned u = fbits(f);
  unsigned r = u + 0x7FFFu + ((u >> 16) & 1u);
  return (unsigned short)(r >> 16);
}
__device__ __forceinline__ float bf2f(unsigned short h) {
  return ffrom((unsigned)h << 16);
}

// Detect whether index buffers are int64 (JAX x64) or int32.
__global__ void detect_idx64_kernel(const void* __restrict__ src, int E,
                                    long long nmax, int* __restrict__ flag) {
  if (threadIdx.x == 0 && blockIdx.x == 0) {
    const long long* p = (const long long*)src;
    int n = E < 512 ? E : 512;
    int ok = 1;
    for (int i = 0; i < n; ++i) {
      long long v = p[i];
      if (v < 0 || v >= nmax) { ok = 0; break; }
    }
    *flag = ok;
  }
}

__device__ __forceinline__ int load_idx(const void* p, int i, int flag) {
  return flag ? (int)((const long long*)p)[i] : ((const int*)p)[i];
}

__global__ void hist_kernel(const void* __restrict__ dstv,
                            const int* __restrict__ flag,
                            int* __restrict__ cnt, int E) {
  int e = blockIdx.x * 256 + threadIdx.x;
  if (e >= E) return;
  atomicAdd(&cnt[load_idx(dstv, e, *flag)], 1);
}

// ---- exclusive scan over cnt[n] -> offs[n], 1024 items / block ----
__global__ __launch_bounds__(256) void scan_reduce(const int* __restrict__ cnt,
                                                   int n, int* __restrict__ bsum) {
  __shared__ int s[256];
  int t = threadIdx.x;
  int base = blockIdx.x * 1024 + t * 4;
  int v = 0;
  if (base + 3 < n) {
    int4 c = *(const int4*)(cnt + base);
    v = c.x + c.y + c.z + c.w;
  } else {
    for (int i = 0; i < 4; ++i)
      if (base + i < n) v += cnt[base + i];
  }
  s[t] = v;
  __syncthreads();
  for (int off = 128; off > 0; off >>= 1) {
    if (t < off) s[t] += s[t + off];
    __syncthreads();
  }
  if (t == 0) bsum[blockIdx.x] = s[0];
}

__global__ void scan_bsums(int* __restrict__ bsum, int nb) {
  if (threadIdx.x == 0 && blockIdx.x == 0) {
    int acc = 0;
    for (int i = 0; i < nb; ++i) {
      int t = bsum[i];
      bsum[i] = acc;
      acc += t;
    }
  }
}

__global__ __launch_bounds__(256) void scan_final(const int* __restrict__ cnt,
                                                  int n, const int* __restrict__ bsum,
                                                  int* __restrict__ offs) {
  __shared__ int s[256];
  int t = threadIdx.x;
  int base = blockIdx.x * 1024 + t * 4;
  int v0 = 0, v1 = 0, v2 = 0, v3 = 0;
  if (base + 3 < n) {
    int4 c = *(const int4*)(cnt + base);
    v0 = c.x; v1 = c.y; v2 = c.z; v3 = c.w;
  } else {
    if (base + 0 < n) v0 = cnt[base + 0];
    if (base + 1 < n) v1 = cnt[base + 1];
    if (base + 2 < n) v2 = cnt[base + 2];
  }
  int tsum = v0 + v1 + v2 + v3;
  s[t] = tsum;
  __syncthreads();
  for (int off = 1; off < 256; off <<= 1) {
    int x = (t >= off) ? s[t - off] : 0;
    __syncthreads();
    s[t] += x;
    __syncthreads();
  }
  int excl = s[t] - tsum;
  int o = bsum[blockIdx.x] + excl;
  if (base + 0 < n) offs[base + 0] = o;
  o += v0;
  if (base + 1 < n) offs[base + 1] = o;
  o += v1;
  if (base + 2 < n) offs[base + 2] = o;
  o += v2;
  if (base + 3 < n) offs[base + 3] = o;
}

// Bucket-fill: advances offs[d]; post-fill offs[d] == pre-fill offs[d+1].
__global__ void fill_kernel(const void* __restrict__ srcv,
                            const void* __restrict__ dstv,
                            const int* __restrict__ flag,
                            int* __restrict__ offs, int* __restrict__ eid, int E) {
  int e = blockIdx.x * 256 + threadIdx.x;
  if (e >= E) return;
  int f = *flag;
  int s = load_idx(srcv, e, f);
  int d = load_idx(dstv, e, f);
  int pos = atomicAdd(&offs[d], 1);
  eid[pos] = s;
}

// One wave per destination row; lane owns cols 2l, 2l+1. Writes mean as
// interleaved split-bf16 row: [hi bf16 x128 | lo bf16 x128] (512 B/row).
__global__ __launch_bounds__(256) void gather_mean_kernel(
    const float* __restrict__ hsrc, const int* __restrict__ offs,
    const int* __restrict__ eid, unsigned short* __restrict__ meanR, int n) {
  int row = blockIdx.x * 4 + (threadIdx.x >> 6);
  if (row >= n) return;
  int lane = threadIdx.x & 63;
  int start = row ? offs[row - 1] : 0;
  int end = offs[row];
  float a0 = 0.f, a1 = 0.f, b0 = 0.f, b1 = 0.f;
  int i = start;
  for (; i + 1 < end; i += 2) {
    const float2 v0 = *(const float2*)(hsrc + (size_t)eid[i] * 128 + lane * 2);
    const float2 v1 = *(const float2*)(hsrc + (size_t)eid[i + 1] * 128 + lane * 2);
    a0 += v0.x; a1 += v0.y;
    b0 += v1.x; b1 += v1.y;
  }
  if (i < end) {
    const float2 v0 = *(const float2*)(hsrc + (size_t)eid[i] * 128 + lane * 2);
    a0 += v0.x; a1 += v0.y;
  }
  a0 += b0; a1 += b1;
  float inv = (end > start) ? 1.0f / (float)(end - start) : 0.0f;
  float m0 = a0 * inv, m1 = a1 * inv;
  unsigned u0 = fbits(m0), u1 = fbits(m1);
  unsigned hw = (u0 >> 16) | (u1 & 0xFFFF0000u);  // trunc split, hi
  float r0 = m0 - ffrom(u0 & 0xFFFF0000u);
  float r1 = m1 - ffrom(u1 & 0xFFFF0000u);
  unsigned lw = (fbits(r0) >> 16) | (fbits(r1) & 0xFFFF0000u);
  unsigned short* rp = meanR + (size_t)row * 256;
  *(unsigned*)(rp + lane * 2) = hw;
  *(unsigned*)(rp + 128 + lane * 2) = lw;
}

// Pre-pack weights (all 3 layers) into per-lane MFMA B-fragment order,
// split bf16 hi/lo (round-to-nearest). Per layer: Wlh|Wll|Wrh|Wrl x16384 u16.
// chunk idx = ((ks*8+cf)*64 + l)*8 + j ; k = ks*32+(l>>4)*8+j ; col = cf*16+(l&15).
__global__ void pack_w3_kernel(const float* __restrict__ Wl1, const float* __restrict__ Wr1,
                               const float* __restrict__ Wl2, const float* __restrict__ Wr2,
                               const float* __restrict__ Wl3, const float* __restrict__ Wr3,
                               unsigned short* __restrict__ wpk) {
  int idx = blockIdx.x * 256 + threadIdx.x;
  if (idx >= 3 * 16384) return;
  int L = idx >> 14;
  int r = idx & 16383;
  const float* Wl = L == 0 ? Wl1 : (L == 1 ? Wl2 : Wl3);
  const float* Wr = L == 0 ? Wr1 : (L == 1 ? Wr2 : Wr3);
  unsigned short* o = wpk + L * 65536;
  int j = r & 7, l = (r >> 3) & 63, cf = (r >> 9) & 7, ks = r >> 12;
  int k = ks * 32 + (l >> 4) * 8 + j;
  int col = cf * 16 + (l & 15);
  float vl = Wl[k * 128 + col];
  float vr = Wr[k * 128 + col];
  unsigned short h = f2bf(vl);
  o[r] = h;
  o[16384 + r] = f2bf(vl - bf2f(h));
  h = f2bf(vr);
  o[32768 + r] = h;
  o[49152 + r] = f2bf(vr - bf2f(h));
}

// MFMA compute: 4 waves/block, each wave owns 32 rows (2x 16-row tiles) so
// B-fragments amortize over 12 MFMAs per 4 loads. Mean A-frags load directly
// from the interleaved split rows (no conversion); x converts fp32->split
// in-register (truncation). out (fp32) may alias meanR: each wave reads only
// its own rows and all reads precede its epilogue stores.
__global__ __launch_bounds__(256) void compute_mfma2_kernel(
    const unsigned short* __restrict__ meanR, const float* __restrict__ xdst,
    const unsigned short* __restrict__ W,
    const float* __restrict__ bias, const float* __restrict__ alpha,
    float* __restrict__ out, int n) {
  const int lane = threadIdx.x & 63;
  const int wv = threadIdx.x >> 6;
  const int rbase = blockIdx.x * 128 + wv * 32;
  const int kb = (lane >> 4) * 8;
  const int arow0 = rbase + (lane & 15);

  f32x4 acc[2][8] = {};

  for (int ks = 0; ks < 4; ++ks) {
    const int k = ks * 32 + kb;
    bf16x8 mh[2], ml[2], xh[2], xl[2];
#pragma unroll
    for (int t = 0; t < 2; ++t) {
      const int ar = arow0 + t * 16;
      if (ar < n) {
        const unsigned short* rp = meanR + (size_t)ar * 256 + k;
        mh[t] = *(const bf16x8*)(rp);
        ml[t] = *(const bf16x8*)(rp + 128);
        const float* xp = xdst + (size_t)ar * 128 + k;
        float xv[8];
        *(float4*)&xv[0] = *(const float4*)(xp);
        *(float4*)&xv[4] = *(const float4*)(xp + 4);
        u32x4 hwv, lwv;
#pragma unroll
        for (int p = 0; p < 4; ++p) {
          unsigned ue = fbits(xv[2 * p]), uo = fbits(xv[2 * p + 1]);
          hwv[p] = (ue >> 16) | (uo & 0xFFFF0000u);
          float re = xv[2 * p] - ffrom(ue & 0xFFFF0000u);
          float ro = xv[2 * p + 1] - ffrom(uo & 0xFFFF0000u);
          lwv[p] = (fbits(re) >> 16) | (fbits(ro) & 0xFFFF0000u);
        }
        xh[t] = __builtin_bit_cast(bf16x8, hwv);
        xl[t] = __builtin_bit_cast(bf16x8, lwv);
      } else {
        mh[t] = (bf16x8)0; ml[t] = (bf16x8)0;
        xh[t] = (bf16x8)0; xl[t] = (bf16x8)0;
      }
    }
    const unsigned short* wb = W + (size_t)ks * 4096 + (size_t)lane * 8;
#pragma unroll
    for (int cf = 0; cf < 8; ++cf) {
      const unsigned short* wp = wb + cf * 512;
      bf16x8 wlh = *(const bf16x8*)(wp);
      bf16x8 wll = *(const bf16x8*)(wp + 16384);
      bf16x8 wrh = *(const bf16x8*)(wp + 32768);
      bf16x8 wrl = *(const bf16x8*)(wp + 49152);
#pragma unroll
      for (int t = 0; t < 2; ++t) {
        acc[t][cf] = __builtin_amdgcn_mfma_f32_16x16x32_bf16(mh[t], wlh, acc[t][cf], 0, 0, 0);
        acc[t][cf] = __builtin_amdgcn_mfma_f32_16x16x32_bf16(ml[t], wlh, acc[t][cf], 0, 0, 0);
        acc[t][cf] = __builtin_amdgcn_mfma_f32_16x16x32_bf16(mh[t], wll, acc[t][cf], 0, 0, 0);
        acc[t][cf] = __builtin_amdgcn_mfma_f32_16x16x32_bf16(xh[t], wrh, acc[t][cf], 0, 0, 0);
        acc[t][cf] = __builtin_amdgcn_mfma_f32_16x16x32_bf16(xl[t], wrh, acc[t][cf], 0, 0, 0);
        acc[t][cf] = __builtin_amdgcn_mfma_f32_16x16x32_bf16(xh[t], wrl, acc[t][cf], 0, 0, 0);
      }
    }
  }

  // Epilogue: C/D layout col = lane&15, row = (lane>>4)*4 + i (verified).
  const int ocol0 = lane & 15;
  const int orow_off = (lane >> 4) * 4;
#pragma unroll
  for (int cf = 0; cf < 8; ++cf) {
    const int ocol = cf * 16 + ocol0;
    const float b = bias[ocol];
    const float a = alpha[ocol];
#pragma unroll
    for (int t = 0; t < 2; ++t) {
      const int orb = rbase + t * 16 + orow_off;
#pragma unroll
      for (int i = 0; i < 4; ++i) {
        const int orow = orb + i;
        if (orow < n) {
          float v = acc[t][cf][i] + b;
          out[(size_t)orow * 128 + ocol] = v > 0.f ? v : a * v;
        }
      }
    }
  }
}

static void run_layer(const float* hsrc, const float* xdst, const void* src,
                      const void* dst, const int* flag, int E, int n,
                      int* cnt, int* offs, int* eid, int* bsum,
                      unsigned short* meanR, const unsigned short* Wpk,
                      const float* b, const float* a, float* out,
                      hipStream_t stream) {
  int nb = NDIV_UP(n, 1024);
  hipMemsetAsync(cnt, 0, (size_t)n * sizeof(int), stream);
  hist_kernel<<<NDIV_UP(E, 256), 256, 0, stream>>>(dst, flag, cnt, E);
  scan_reduce<<<nb, 256, 0, stream>>>(cnt, n, bsum);
  scan_bsums<<<1, 64, 0, stream>>>(bsum, nb);
  scan_final<<<nb, 256, 0, stream>>>(cnt, n, bsum, offs);
  fill_kernel<<<NDIV_UP(E, 256), 256, 0, stream>>>(src, dst, flag, offs, eid, E);
  gather_mean_kernel<<<NDIV_UP(n, 4), 256, 0, stream>>>(hsrc, offs, eid, meanR, n);
  compute_mfma2_kernel<<<NDIV_UP(n, 128), 256, 0, stream>>>(
      meanR, xdst, Wpk, b, a, out, n);
}

extern "C" void kernel_launch(void* const* d_in, const int* in_sizes, int n_in,
                              void* d_out, int out_size, void* d_ws, size_t ws_size,
                              hipStream_t stream) {
  const float* x = (const float*)d_in[0];
  const void* src1 = d_in[1];
  const void* dst1 = d_in[2];
  const void* src2 = d_in[3];
  const void* dst2 = d_in[4];
  const void* src3 = d_in[5];
  const void* dst3 = d_in[6];
  const float* Wl1 = (const float*)d_in[7];
  const float* Wr1 = (const float*)d_in[8];
  const float* b1  = (const float*)d_in[9];
  const float* a1  = (const float*)d_in[10];
  const float* Wl2 = (const float*)d_in[11];
  const float* Wr2 = (const float*)d_in[12];
  const float* b2  = (const float*)d_in[13];
  const float* a2  = (const float*)d_in[14];
  const float* Wl3 = (const float*)d_in[15];
  const float* Wr3 = (const float*)d_in[16];
  const float* b3  = (const float*)d_in[17];
  const float* a3  = (const float*)d_in[18];

  // ws layout (bytes):
  //   R1: N1*512 (mean1 split rows, then h1 fp32 in-place)
  //   R2: N2*512 (mean2 split rows, then h2 fp32 in-place; mean3 reuses R1)
  //   cnt, offs (N1 ints), eid (E1 ints), bsum (1024 i), flag (64 i), wpk
  unsigned short* R1 = (unsigned short*)d_ws;
  unsigned short* R2 = R1 + (size_t)cN1 * 256;
  int* cnt = (int*)(R2 + (size_t)cN2 * 256);
  int* offs = cnt + cN1;
  int* eid = offs + cN1;
  int* bsum = eid + cE1;
  int* flag = bsum + 1024;
  unsigned short* wpk = (unsigned short*)(flag + 64);

  detect_idx64_kernel<<<1, 64, 0, stream>>>(src1, cE1, (long long)cN0, flag);
  pack_w3_kernel<<<192, 256, 0, stream>>>(Wl1, Wr1, Wl2, Wr2, Wl3, Wr3, wpk);

  // Layer 1: x (N0) -> h1 fp32 in R1
  run_layer(x, x, src1, dst1, flag, cE1, cN1, cnt, offs, eid, bsum,
            R1, wpk, b1, a1, (float*)R1, stream);
  // Layer 2: h1 -> h2 fp32 in R2
  run_layer((const float*)R1, (const float*)R1, src2, dst2, flag, cE2, cN2,
            cnt, offs, eid, bsum, R2, wpk + 65536, b2, a2, (float*)R2, stream);
  // Layer 3: h2 -> out (d_out), mean3 in R1
  run_layer((const float*)R2, (const float*)R2, src3, dst3, flag, cE3, cN3,
            cnt, offs, eid, bsum, R1, wpk + 131072, b3, a3, (float*)d_out, stream);
}